// Round 5
// baseline (1250.692 us; speedup 1.0000x reference)
//
#include <hip/hip_runtime.h>
#include <cmath>
#include <utility>

// SSIM + L1 image similarity loss, MI355X (gfx950).
// es, ta: fp32 [16,3,512,512]. Output: out[0]=l1_loss, out[1]=ssim_loss.
//
// R5: R1-R4 post-mortem showed dur == (#global atomicAdds to accbuf) * 13.3ns
// -- the same-address device atomics serialized the whole grid (655us for
// 49152 atomics; R1's 24576 -> 354us). Compute was never the bottleneck.
// Fix: NO global atomics. Per-block reduce (shfl -> LDS -> thread0) and one
// float2 partial store per block into d_ws; 1-block finalize kernel reduces
// the partials and writes out[0..1]. Compute structure = R4 (absmax 0.0).

constexpr int TILE_W = 64;
constexpr int TILE_H = 32;
constexpr int HALO = 5;
constexpr int WIN  = 11;
constexpr int LH   = TILE_H + 2 * HALO;  // 42 staged rows
constexpr int LW   = TILE_W + 2 * HALO;  // 74 staged cols
constexpr int LSTR = 76;                 // LDS row stride (float2 units)
constexpr int IMG  = 512;
constexpr int ROWS_PER_WAVE = 8;         // 4 waves x 8 rows = 32
constexpr int STREAM_ROWS = ROWS_PER_WAVE + WIN - 1;  // 18
constexpr float C1C = 0.01f * 0.01f;
constexpr float C2C = 0.03f * 0.03f;

struct Wnd { float g[WIN]; };

template<class F, int... I>
__device__ inline void unroll_impl(F&& f, std::integer_sequence<int, I...>) {
    (f(std::integral_constant<int, I>{}), ...);
}
template<int N, class F>
__device__ inline void s_unroll(F&& f) {
    unroll_impl(static_cast<F&&>(f), std::make_integer_sequence<int, N>{});
}

__global__ __launch_bounds__(256, 4) void ssim_main(
    const float* __restrict__ es, const float* __restrict__ ta,
    float2* __restrict__ partials, Wnd w)
{
    __shared__ float2 sS[LH * LSTR];
    __shared__ float2 red[4];

    const int tid = threadIdx.x;
    const int tx0 = blockIdx.x * TILE_W;
    const int ty0 = blockIdx.y * TILE_H;
    const int img = blockIdx.z;
    const float* pe = es + (size_t)img * (IMG * IMG);
    const float* pt = ta + (size_t)img * (IMG * IMG);

    // ---- stage interleaved {e,t} tile (zero-pad outside image) ----
    for (int i = tid; i < LH * LW; i += 256) {
        int r = i / LW;
        int c = i - r * LW;
        int gy = ty0 - HALO + r;
        int gx = tx0 - HALO + c;
        float ev = 0.f, tv = 0.f;
        if (gy >= 0 && gy < IMG && gx >= 0 && gx < IMG) {
            int off = gy * IMG + gx;
            ev = pe[off];
            tv = pt[off];
        }
        sS[r * LSTR + c] = make_float2(ev, tv);
    }
    __syncthreads();

    const int wv = tid >> 6;   // wave id 0..3 -> 8-row segment
    const int ln = tid & 63;   // lane -> column
    const int rbase = wv * ROWS_PER_WAVE;
    const float2* rp = &sS[rbase * LSTR + ln];  // one base addr; rest immediates

    float a0[ROWS_PER_WAVE], a1[ROWS_PER_WAVE], a2[ROWS_PER_WAVE],
          a3[ROWS_PER_WAVE], a4[ROWS_PER_WAVE];
    float ssim_s = 0.f, l1_s = 0.f;

    s_unroll<STREAM_ROWS>([&](auto rrc) {
        constexpr int rr = decltype(rrc)::value;

        // horizontal 11-tap of {e, t, e^2, t^2, e*t} for streamed row rr
        float hm1 = 0.f, hm2 = 0.f, h11 = 0.f, h22 = 0.f, h12 = 0.f;
        s_unroll<WIN>([&](auto kc) {
            constexpr int k = decltype(kc)::value;
            float2 v = rp[rr * LSTR + k];       // ds_read_b64, imm offset
            float gk = w.g[k];
            float ge = gk * v.x;
            float gt = gk * v.y;
            hm1 += ge;
            hm2 += gt;
            h11 += ge * v.x;
            h22 += gt * v.y;
            h12 += ge * v.y;
        });

        // vertical scatter: streamed row rr feeds output rows rr-10..rr
        s_unroll<WIN>([&](auto kc) {
            constexpr int k = decltype(kc)::value;
            constexpr int o = rr - k;
            if constexpr (o >= 0 && o < ROWS_PER_WAVE) {
                float gk = w.g[k];
                if constexpr (k == 0) {         // first touch of row o
                    a0[o] = gk * hm1;
                    a1[o] = gk * hm2;
                    a2[o] = gk * h11;
                    a3[o] = gk * h22;
                    a4[o] = gk * h12;
                } else {
                    a0[o] += gk * hm1;
                    a1[o] += gk * hm2;
                    a2[o] += gk * h11;
                    a3[o] += gk * h22;
                    a4[o] += gk * h12;
                }
            }
        });

        // early finalize: output row o = rr-10 is complete; free its regs
        if constexpr (rr >= WIN - 1) {
            constexpr int o = rr - (WIN - 1);
            float mu1 = a0[o], mu2 = a1[o];
            float m11 = mu1 * mu1, m22 = mu2 * mu2, m12 = mu1 * mu2;
            float s11 = a2[o] - m11;
            float s22 = a3[o] - m22;
            float s12 = a4[o] - m12;
            float num = (2.f * m12 + C1C) * (2.f * s12 + C2C);
            float den = (m11 + m22 + C1C) * (s11 + s22 + C2C);
            ssim_s += num * __builtin_amdgcn_rcpf(den);

            float2 c = rp[(o + HALO) * LSTR + HALO];  // center pixel {e,t}
            l1_s += fabsf(c.x - c.y);
        }
    });

    // ---- block reduce: wave shfl -> LDS[4] -> thread 0 stores partial ----
    #pragma unroll
    for (int off = 32; off >= 1; off >>= 1) {
        ssim_s += __shfl_xor(ssim_s, off, 64);
        l1_s   += __shfl_xor(l1_s, off, 64);
    }
    if (ln == 0) red[wv] = make_float2(ssim_s, l1_s);
    __syncthreads();
    if (tid == 0) {
        float2 r0 = red[0], r1 = red[1], r2 = red[2], r3 = red[3];
        float2 p = make_float2(r0.x + r1.x + r2.x + r3.x,
                               r0.y + r1.y + r2.y + r3.y);
        int bid = (blockIdx.z * gridDim.y + blockIdx.y) * gridDim.x + blockIdx.x;
        partials[bid] = p;
    }
}

__global__ __launch_bounds__(256) void ssim_reduce(
    const float2* __restrict__ partials, int n, float* __restrict__ out)
{
    __shared__ float2 red[4];
    const int tid = threadIdx.x;
    float ssim_s = 0.f, l1_s = 0.f;
    for (int i = tid; i < n; i += 256) {
        float2 p = partials[i];
        ssim_s += p.x;
        l1_s   += p.y;
    }
    #pragma unroll
    for (int off = 32; off >= 1; off >>= 1) {
        ssim_s += __shfl_xor(ssim_s, off, 64);
        l1_s   += __shfl_xor(l1_s, off, 64);
    }
    if ((tid & 63) == 0) red[tid >> 6] = make_float2(ssim_s, l1_s);
    __syncthreads();
    if (tid == 0) {
        float s = red[0].x + red[1].x + red[2].x + red[3].x;
        float l = red[0].y + red[1].y + red[2].y + red[3].y;
        const float N = 16.f * 3.f * 512.f * 512.f;
        out[0] = 0.15f * (l / N);
        out[1] = 0.85f * 0.5f * (1.f - s / N);
    }
}

extern "C" void kernel_launch(void* const* d_in, const int* in_sizes, int n_in,
                              void* d_out, int out_size, void* d_ws, size_t ws_size,
                              hipStream_t stream)
{
    const float* es = (const float*)d_in[0];
    const float* ta = (const float*)d_in[1];
    float* out = (float*)d_out;
    float2* partials = (float2*)d_ws;

    Wnd w;
    double gd[WIN], sum = 0.0;
    for (int i = 0; i < WIN; ++i) {
        double x = (double)(i - WIN / 2);
        gd[i] = std::exp(-(x * x) / (2.0 * 1.5 * 1.5));
        sum += gd[i];
    }
    for (int i = 0; i < WIN; ++i) w.g[i] = (float)(gd[i] / sum);

    const int nimg = in_sizes[0] / (IMG * IMG);  // 16*3 = 48
    dim3 grid(IMG / TILE_W, IMG / TILE_H, nimg);
    const int nblocks = grid.x * grid.y * grid.z;  // 6144 partials
    ssim_main<<<grid, 256, 0, stream>>>(es, ta, partials, w);
    ssim_reduce<<<1, 256, 0, stream>>>(partials, nblocks, out);
}

// Round 6
// 223.850 us; speedup vs baseline: 5.5872x; 5.5872x over previous
//
#include <hip/hip_runtime.h>
#include <cmath>

// SSIM + L1 image similarity loss, MI355X (gfx950).
// es, ta: fp32 [16,3,512,512]. Output: out[0]=l1_loss, out[1]=ssim_loss.
//
// R6: controlled experiment. R1 was the only healthy codegen (VGPR=72,
// FETCH=102MB compulsory, no scratch) and its 354us == atomic floor
// (24576 same-address atomicAdds x 13.3ns). R5 proved atomic removal works
// but its lambda-unroll machinery spilled 4.3GB of scratch.
// => R1's EXACT kernel (plain #pragma unroll, 64x64 tile, 4 waves x 16
// rows, no min-wave bound), only the tail changed: wave shfl -> red[4]
// LDS -> one float2 partial per block -> 1-block reduce kernel.

constexpr int TILE = 64;
constexpr int HALO = 5;
constexpr int WIN  = 11;
constexpr int LW   = TILE + 2 * HALO;  // 74
constexpr int LSTR = 76;               // padded LDS row stride
constexpr int IMG  = 512;
constexpr float C1C = 0.01f * 0.01f;
constexpr float C2C = 0.03f * 0.03f;

struct Wnd { float g[WIN]; };

__global__ __launch_bounds__(256) void ssim_main(
    const float* __restrict__ es, const float* __restrict__ ta,
    float2* __restrict__ partials, Wnd w)
{
    __shared__ float sA[LW * LSTR];
    __shared__ float sB[LW * LSTR];
    __shared__ float2 red[4];

    const int tid = threadIdx.x;
    const int tx0 = blockIdx.x * TILE;
    const int ty0 = blockIdx.y * TILE;
    const int img = blockIdx.z;
    const float* pe = es + (size_t)img * (IMG * IMG);
    const float* pt = ta + (size_t)img * (IMG * IMG);

    // ---- stage input tiles (zero-pad outside image) ----
    for (int i = tid; i < LW * LW; i += 256) {
        int r = i / LW;
        int c = i - r * LW;
        int gy = ty0 - HALO + r;
        int gx = tx0 - HALO + c;
        float ev = 0.f, tv = 0.f;
        if (gy >= 0 && gy < IMG && gx >= 0 && gx < IMG) {
            int off = gy * IMG + gx;
            ev = pe[off];
            tv = pt[off];
        }
        sA[r * LSTR + c] = ev;
        sB[r * LSTR + c] = tv;
    }
    __syncthreads();

    const int wv = tid >> 6;   // wave id 0..3 -> 16-row segment
    const int ln = tid & 63;   // lane -> column

    float a0[16], a1[16], a2[16], a3[16], a4[16];
    #pragma unroll
    for (int o = 0; o < 16; ++o) { a0[o]=0.f; a1[o]=0.f; a2[o]=0.f; a3[o]=0.f; a4[o]=0.f; }

    const int rbase = wv * 16;

    #pragma unroll
    for (int rr = 0; rr < 26; ++rr) {
        const float* rowA = &sA[(rbase + rr) * LSTR + ln];
        const float* rowB = &sB[(rbase + rr) * LSTR + ln];
        float e[WIN], t[WIN];
        #pragma unroll
        for (int k = 0; k < WIN; ++k) { e[k] = rowA[k]; t[k] = rowB[k]; }

        float hm1 = 0.f, hm2 = 0.f, h11 = 0.f, h22 = 0.f, h12 = 0.f;
        #pragma unroll
        for (int k = 0; k < WIN; ++k) {
            float gk = w.g[k];
            float ge = gk * e[k];
            float gt = gk * t[k];
            hm1 += ge;
            hm2 += gt;
            h11 += ge * e[k];
            h22 += gt * t[k];
            h12 += ge * t[k];
        }

        // vertical scatter: input row rr contributes g[k] to output row rr-k
        #pragma unroll
        for (int k = 0; k < WIN; ++k) {
            int o = rr - k;
            if (o >= 0 && o < 16) {
                float gk = w.g[k];
                a0[o] += gk * hm1;
                a1[o] += gk * hm2;
                a2[o] += gk * h11;
                a3[o] += gk * h22;
                a4[o] += gk * h12;
            }
        }
    }

    // ---- epilogue: ssim per pixel + L1, then reduce ----
    float ssim_s = 0.f, l1_s = 0.f;
    #pragma unroll
    for (int o = 0; o < 16; ++o) {
        float mu1 = a0[o], mu2 = a1[o];
        float m11 = mu1 * mu1, m22 = mu2 * mu2, m12 = mu1 * mu2;
        float s11 = a2[o] - m11;
        float s22 = a3[o] - m22;
        float s12 = a4[o] - m12;
        float num = (2.f * m12 + C1C) * (2.f * s12 + C2C);
        float den = (m11 + m22 + C1C) * (s11 + s22 + C2C);
        ssim_s += num * __builtin_amdgcn_rcpf(den);

        int lr = rbase + o + HALO;
        float ev = sA[lr * LSTR + ln + HALO];
        float tv = sB[lr * LSTR + ln + HALO];
        l1_s += fabsf(ev - tv);
    }

    // ---- block reduce: wave shfl -> LDS[4] -> thread 0 stores partial ----
    #pragma unroll
    for (int off = 32; off >= 1; off >>= 1) {
        ssim_s += __shfl_xor(ssim_s, off, 64);
        l1_s   += __shfl_xor(l1_s, off, 64);
    }
    if (ln == 0) red[wv] = make_float2(ssim_s, l1_s);
    __syncthreads();
    if (tid == 0) {
        float2 r0 = red[0], r1 = red[1], r2 = red[2], r3 = red[3];
        float2 p = make_float2(r0.x + r1.x + r2.x + r3.x,
                               r0.y + r1.y + r2.y + r3.y);
        int bid = (blockIdx.z * gridDim.y + blockIdx.y) * gridDim.x + blockIdx.x;
        partials[bid] = p;
    }
}

__global__ __launch_bounds__(256) void ssim_reduce(
    const float2* __restrict__ partials, int n, float* __restrict__ out)
{
    __shared__ float2 red[4];
    const int tid = threadIdx.x;
    float ssim_s = 0.f, l1_s = 0.f;
    for (int i = tid; i < n; i += 256) {
        float2 p = partials[i];
        ssim_s += p.x;
        l1_s   += p.y;
    }
    #pragma unroll
    for (int off = 32; off >= 1; off >>= 1) {
        ssim_s += __shfl_xor(ssim_s, off, 64);
        l1_s   += __shfl_xor(l1_s, off, 64);
    }
    if ((tid & 63) == 0) red[tid >> 6] = make_float2(ssim_s, l1_s);
    __syncthreads();
    if (tid == 0) {
        float s = red[0].x + red[1].x + red[2].x + red[3].x;
        float l = red[0].y + red[1].y + red[2].y + red[3].y;
        const float N = 16.f * 3.f * 512.f * 512.f;
        out[0] = 0.15f * (l / N);
        out[1] = 0.85f * 0.5f * (1.f - s / N);
    }
}

extern "C" void kernel_launch(void* const* d_in, const int* in_sizes, int n_in,
                              void* d_out, int out_size, void* d_ws, size_t ws_size,
                              hipStream_t stream)
{
    const float* es = (const float*)d_in[0];
    const float* ta = (const float*)d_in[1];
    float* out = (float*)d_out;
    float2* partials = (float2*)d_ws;

    Wnd w;
    double gd[WIN], sum = 0.0;
    for (int i = 0; i < WIN; ++i) {
        double x = (double)(i - WIN / 2);
        gd[i] = std::exp(-(x * x) / (2.0 * 1.5 * 1.5));
        sum += gd[i];
    }
    for (int i = 0; i < WIN; ++i) w.g[i] = (float)(gd[i] / sum);

    const int nimg = in_sizes[0] / (IMG * IMG);  // 16*3 = 48
    dim3 grid(IMG / TILE, IMG / TILE, nimg);     // 8 x 8 x 48 = 3072 blocks
    const int nblocks = grid.x * grid.y * grid.z;
    ssim_main<<<grid, 256, 0, stream>>>(es, ta, partials, w);
    ssim_reduce<<<1, 256, 0, stream>>>(partials, nblocks, out);
}

// Round 7
// 114.590 us; speedup vs baseline: 10.9144x; 1.9535x over previous
//
#include <hip/hip_runtime.h>
#include <cmath>

// SSIM + L1 image similarity loss, MI355X (gfx950).
// es, ta: fp32 [16,3,512,512]. Output: out[0]=l1_loss, out[1]=ssim_loss.
//
// R7: R6 fixed the atomic wall (655->224us) but is latency-bound at 8
// waves/CU (VGPR 212 -> 2/SIMD; 45KB LDS -> 2 blocks/CU), VALUBusy 40%.
// Changes (occupancy x2):
//  - circular 11-slot h-window (55 regs) replaces 80 accumulators: compute
//    horizontal sums once per streamed row, gather output row rr-10 with
//    55 FMAs. Same FLOPs, peak live ~75 -> target VGPR <=128 (4 waves/SIMD).
//  - 64x48 tile, float2-interleaved LDS (58x76x8 = 35.3KB) -> 4 blocks/CU.
//  - launch_bounds(256,4): cap 128, ample headroom over live set.
//  - last y-stripe (512 = 10*48+32) guards invalid rows (padded rows would
//    contribute ssim=1 each -- correctness, wave-uniform branch).

constexpr int TILE_W = 64;
constexpr int TILE_H = 48;
constexpr int HALO = 5;
constexpr int WIN  = 11;
constexpr int ROWS_PER_WAVE = TILE_H / 4;          // 12
constexpr int STREAM_ROWS = ROWS_PER_WAVE + WIN - 1; // 22
constexpr int LH   = TILE_H + 2 * HALO;  // 58 staged rows
constexpr int LW   = TILE_W + 2 * HALO;  // 74 staged cols
constexpr int LSTR = 76;                 // LDS row stride (float2 units)
constexpr int IMG  = 512;
constexpr float C1C = 0.01f * 0.01f;
constexpr float C2C = 0.03f * 0.03f;

struct Wnd { float g[WIN]; };

__global__ __launch_bounds__(256, 4) void ssim_main(
    const float* __restrict__ es, const float* __restrict__ ta,
    float2* __restrict__ partials, Wnd w)
{
    __shared__ float2 sS[LH * LSTR];
    __shared__ float2 red[4];

    const int tid = threadIdx.x;
    const int tx0 = blockIdx.x * TILE_W;
    const int ty0 = blockIdx.y * TILE_H;
    const int img = blockIdx.z;
    const float* pe = es + (size_t)img * (IMG * IMG);
    const float* pt = ta + (size_t)img * (IMG * IMG);

    // ---- stage interleaved {e,t} tile (zero-pad outside image) ----
    for (int i = tid; i < LH * LW; i += 256) {
        int r = i / LW;
        int c = i - r * LW;
        int gy = ty0 - HALO + r;
        int gx = tx0 - HALO + c;
        float ev = 0.f, tv = 0.f;
        if (gy >= 0 && gy < IMG && gx >= 0 && gx < IMG) {
            int off = gy * IMG + gx;
            ev = pe[off];
            tv = pt[off];
        }
        sS[r * LSTR + c] = make_float2(ev, tv);
    }
    __syncthreads();

    const int wv = tid >> 6;   // wave id 0..3 -> 12-row segment
    const int ln = tid & 63;   // lane -> column
    const int rbase = wv * ROWS_PER_WAVE;
    const float2* rp = &sS[rbase * LSTR + ln];

    float hw[5][WIN];          // circular window of horizontal sums
    float ssim_s = 0.f, l1_s = 0.f;

    #pragma unroll
    for (int rr = 0; rr < STREAM_ROWS; ++rr) {
        // horizontal 11-tap of {e, t, e^2, t^2, e*t} for streamed row rr
        float hm1 = 0.f, hm2 = 0.f, h11 = 0.f, h22 = 0.f, h12 = 0.f;
        #pragma unroll
        for (int k = 0; k < WIN; ++k) {
            float2 v = rp[rr * LSTR + k];   // ds_read_b64, imm offset
            float gk = w.g[k];
            float ge = gk * v.x;
            float gt = gk * v.y;
            hm1 += ge;
            hm2 += gt;
            h11 += ge * v.x;
            h22 += gt * v.y;
            h12 += ge * v.y;
        }
        const int s = rr % WIN;            // constant after unroll
        hw[0][s] = hm1; hw[1][s] = hm2; hw[2][s] = h11;
        hw[3][s] = h22; hw[4][s] = h12;

        if (rr >= WIN - 1) {
            const int o = rr - (WIN - 1);  // completed output row
            float mu1 = 0.f, mu2 = 0.f, x11 = 0.f, x22 = 0.f, x12 = 0.f;
            #pragma unroll
            for (int k = 0; k < WIN; ++k) {
                const int idx = (o + k) % WIN;  // constant after unroll
                float gk = w.g[k];
                mu1 += gk * hw[0][idx];
                mu2 += gk * hw[1][idx];
                x11 += gk * hw[2][idx];
                x22 += gk * hw[3][idx];
                x12 += gk * hw[4][idx];
            }
            if (ty0 + rbase + o < IMG) {   // skip padded rows (last stripe)
                float m11 = mu1 * mu1, m22 = mu2 * mu2, m12 = mu1 * mu2;
                float s11 = x11 - m11;
                float s22 = x22 - m22;
                float s12 = x12 - m12;
                float num = (2.f * m12 + C1C) * (2.f * s12 + C2C);
                float den = (m11 + m22 + C1C) * (s11 + s22 + C2C);
                ssim_s += num * __builtin_amdgcn_rcpf(den);

                float2 c = rp[(o + HALO) * LSTR + HALO];  // center {e,t}
                l1_s += fabsf(c.x - c.y);
            }
        }
    }

    // ---- block reduce: wave shfl -> LDS[4] -> thread 0 stores partial ----
    #pragma unroll
    for (int off = 32; off >= 1; off >>= 1) {
        ssim_s += __shfl_xor(ssim_s, off, 64);
        l1_s   += __shfl_xor(l1_s, off, 64);
    }
    if (ln == 0) red[wv] = make_float2(ssim_s, l1_s);
    __syncthreads();
    if (tid == 0) {
        float2 r0 = red[0], r1 = red[1], r2 = red[2], r3 = red[3];
        float2 p = make_float2(r0.x + r1.x + r2.x + r3.x,
                               r0.y + r1.y + r2.y + r3.y);
        int bid = (blockIdx.z * gridDim.y + blockIdx.y) * gridDim.x + blockIdx.x;
        partials[bid] = p;
    }
}

__global__ __launch_bounds__(256) void ssim_reduce(
    const float2* __restrict__ partials, int n, float* __restrict__ out)
{
    __shared__ float2 red[4];
    const int tid = threadIdx.x;
    float ssim_s = 0.f, l1_s = 0.f;
    for (int i = tid; i < n; i += 256) {
        float2 p = partials[i];
        ssim_s += p.x;
        l1_s   += p.y;
    }
    #pragma unroll
    for (int off = 32; off >= 1; off >>= 1) {
        ssim_s += __shfl_xor(ssim_s, off, 64);
        l1_s   += __shfl_xor(l1_s, off, 64);
    }
    if ((tid & 63) == 0) red[tid >> 6] = make_float2(ssim_s, l1_s);
    __syncthreads();
    if (tid == 0) {
        float s = red[0].x + red[1].x + red[2].x + red[3].x;
        float l = red[0].y + red[1].y + red[2].y + red[3].y;
        const float N = 16.f * 3.f * 512.f * 512.f;
        out[0] = 0.15f * (l / N);
        out[1] = 0.85f * 0.5f * (1.f - s / N);
    }
}

extern "C" void kernel_launch(void* const* d_in, const int* in_sizes, int n_in,
                              void* d_out, int out_size, void* d_ws, size_t ws_size,
                              hipStream_t stream)
{
    const float* es = (const float*)d_in[0];
    const float* ta = (const float*)d_in[1];
    float* out = (float*)d_out;
    float2* partials = (float2*)d_ws;

    Wnd w;
    double gd[WIN], sum = 0.0;
    for (int i = 0; i < WIN; ++i) {
        double x = (double)(i - WIN / 2);
        gd[i] = std::exp(-(x * x) / (2.0 * 1.5 * 1.5));
        sum += gd[i];
    }
    for (int i = 0; i < WIN; ++i) w.g[i] = (float)(gd[i] / sum);

    const int nimg = in_sizes[0] / (IMG * IMG);  // 16*3 = 48
    dim3 grid(IMG / TILE_W, (IMG + TILE_H - 1) / TILE_H, nimg);  // 8 x 11 x 48
    const int nblocks = grid.x * grid.y * grid.z;                // 4224
    ssim_main<<<grid, 256, 0, stream>>>(es, ta, partials, w);
    ssim_reduce<<<1, 256, 0, stream>>>(partials, nblocks, out);
}